// Round 16
// baseline (95.962 us; speedup 1.0000x reference)
//
#include <hip/hip_runtime.h>
#include <hip/hip_bf16.h>

#define DEVI __device__ __forceinline__
#define AS1 __attribute__((address_space(1)))
#define AS3 __attribute__((address_space(3)))

typedef float f32x4 __attribute__((ext_vector_type(4)));
typedef _Float16 f16x8 __attribute__((ext_vector_type(8)));
typedef short s16x8 __attribute__((ext_vector_type(8)));

constexpr int NB = 8;     // batch
constexpr int HW = 1024;  // i (query) dim
constexpr int KD = 128;   // QK reduction dim
constexpr int VD = 512;   // value dim
constexpr int NJ = 2048;  // j (key/col) dim
constexpr float LOG2E = 1.44269504088896f;

// Fragment-major layouts: [..tile..][..k-chunk..][lane 64][elem 8]
// QB f16  [2 src][8 b][64 it][4 kc][512]   (pre-scaled by log2(e))
// KT f16  [2 src][8 b][128 jt][4 kc][512]
// MV bf16 [8 b][32 vt][64 jc][512]
// P  bf16 [8 b][64 it][64 kchunk][512]
constexpr size_t WS_KT = 0;                                    // 8.39 MB
constexpr size_t WS_QB = WS_KT + (size_t)2*NB*NJ*KD*2;         // 4.19 MB
constexpr size_t WS_MV = WS_QB + (size_t)2*NB*HW*KD*2;         // 16.78 MB
constexpr size_t WS_D  = WS_MV + (size_t)NB*VD*NJ*2;           // 2.10 MB
constexpr size_t WS_P  = WS_D  + (size_t)4*4*NB*NJ*4;          // 33.55 MB
constexpr size_t WS_NEED = WS_P + (size_t)NB*HW*NJ*2;          // ~65 MB total
constexpr size_t PBF = (size_t)64*64*512;                      // P shorts per batch

DEVI unsigned short f2bf(float x) {
    unsigned int u = __builtin_bit_cast(unsigned int, x);
    u += 0x7fffu + ((u >> 16) & 1u);
    return (unsigned short)(u >> 16);
}

// ---------------- k_prep_kq: KT transpose + QB cvt (stats' inputs only) -------------
// [0,512): KT transpose; [512,640): QB cvt (x LOG2E)
__global__ __launch_bounds__(256) void k_prep_kq(
    const float* __restrict__ k0, const float* __restrict__ k1,
    const float* __restrict__ q0, const float* __restrict__ q1,
    unsigned short* __restrict__ KT, unsigned short* __restrict__ QB) {
    __shared__ _Float16 Lt[128][138];   // 35.3 KB
    int bid = blockIdx.x;
    int t = threadIdx.x;
    int w = t >> 6, l = t & 63, lr = l & 15, lg = l >> 4;

    if (bid < 512) {
        _Float16(*Lk)[136] = (_Float16(*)[136])&Lt[0][0];
        int jt64 = bid & 31, b = (bid >> 5) & 7, src = bid >> 8;
        const float* K = (src ? k1 : k0) + (size_t)b * KD * NJ;
#pragma unroll
        for (int rd = 0; rd < 8; ++rd) {
            int task = t + rd * 256;
            int d = task >> 4, j4 = (task & 15) * 4;
            float4 v = *(const float4*)&K[(size_t)d * NJ + jt64 * 64 + j4];
            Lk[j4 + 0][d] = (_Float16)v.x;
            Lk[j4 + 1][d] = (_Float16)v.y;
            Lk[j4 + 2][d] = (_Float16)v.z;
            Lk[j4 + 3][d] = (_Float16)v.w;
        }
        __syncthreads();
        int jt = jt64 * 4 + w;
#pragma unroll
        for (int kc = 0; kc < 4; ++kc) {
            f16x8 v = *(const f16x8*)&Lk[w * 16 + lr][kc * 32 + lg * 8];
            *(f16x8*)&KT[((((size_t)src * NB + b) * 128 + jt) * 4 + kc) * 512 + l * 8] = v;
        }
        return;
    }
    // ---- QB cvt: tile 128 i x 128 d ----
    int bid3 = bid - 512;
    int itq = bid3 & 7, b = (bid3 >> 3) & 7, src_q = bid3 >> 6;
    const float* q = (src_q ? q1 : q0) + (size_t)(b * HW + itq * 128) * KD;
#pragma unroll
    for (int rd = 0; rd < 16; ++rd) {
        int idx = rd * 256 + t;
        int row = idx >> 5, c4 = (idx & 31) * 4;
        float4 v = *(const float4*)&q[(size_t)row * KD + c4];
        Lt[row][c4 + 0] = (_Float16)(v.x * LOG2E);
        Lt[row][c4 + 1] = (_Float16)(v.y * LOG2E);
        Lt[row][c4 + 2] = (_Float16)(v.z * LOG2E);
        Lt[row][c4 + 3] = (_Float16)(v.w * LOG2E);
    }
    __syncthreads();
#pragma unroll
    for (int rd = 0; rd < 8; ++rd) {
        int f = rd * 4 + w;
        int it_l = f >> 2, kc = f & 3;
        f16x8 v = *(const f16x8*)&Lt[it_l * 16 + lr][kc * 32 + lg * 8];
        *(f16x8*)&QB[((((size_t)src_q * NB + b) * 64 + itq * 8 + it_l) * 4 + kc) * 512 + l * 8] = v;
    }
}

// ---------------- k_stats: INTERLEAVED compute/stream blocks ----------------
// grid 1920 = 15 x 128. bid%15 < 4 -> compute (512 blocks: 256j x 256i x kc x b);
// else stream (1408: MV cvt 1024, qval copy 384). Mixed residency per CU -> overlap.
__global__ __launch_bounds__(256, 4) void k_stats(
    const unsigned short* __restrict__ KTu, const unsigned short* __restrict__ QBu,
    const float* __restrict__ mv, const float* __restrict__ qv,
    float* __restrict__ d_part, unsigned short* __restrict__ MV,
    float* __restrict__ out) {
    __shared__ unsigned short Lv[16][522];   // 16.7 KB (MV section only)
    int bid = blockIdx.x;
    int t = threadIdx.x, w = t >> 6, l = t & 63, lr = l & 15, lg = l >> 4;
    int g = bid / 15, s = bid % 15;

    if (s >= 4) {
        int sid = g * 11 + (s - 4);          // 0..1407
        if (sid < 1024) {
            // ---- MV cvt: tile 16 v x 512 j ----
            int jq = sid & 3, vt = (sid >> 2) & 31, b = sid >> 7;
            const float* src = mv + (size_t)b * VD * NJ + (size_t)(vt * 16) * NJ + jq * 512;
#pragma unroll
            for (int rd = 0; rd < 8; ++rd) {
                int idx = rd * 256 + t;
                int row = idx >> 7, c4 = (idx & 127) * 4;
                float4 v = *(const float4*)&src[(size_t)row * NJ + c4];
                Lv[row][c4 + 0] = f2bf(v.x);
                Lv[row][c4 + 1] = f2bf(v.y);
                Lv[row][c4 + 2] = f2bf(v.z);
                Lv[row][c4 + 3] = f2bf(v.w);
            }
            __syncthreads();
#pragma unroll
            for (int rd = 0; rd < 4; ++rd) {
                int f = rd * 4 + w;
                s16x8 v = *(const s16x8*)&Lv[lr][f * 32 + lg * 8];
                *(s16x8*)&MV[(((size_t)b * 32 + vt) * 64 + jq * 16 + f) * 512 + l * 8] = v;
            }
        } else {
            // ---- qval copy (384 blocks, grid-stride) ----
            const int NQV = NB * VD * HW / 4;
            for (int t3 = (sid - 1024) * 256 + t; t3 < NQV; t3 += 384 * 256) {
                int b = t3 >> 17, t4 = t3 & 131071;
                float4 v = ((const float4*)qv)[t3];
                ((float4*)(out + (size_t)b * 1048576 + 524288))[t4] = v;
            }
        }
        return;
    }
    // ---- compute: column sum of exp2; 4 jt per wave (256 j per block) ----
    int cid = g * 4 + s;                     // 0..511
    int b = cid & 7, r = cid >> 3;
    int jb8 = r & 7, is = (r >> 3) & 3, kc_s = r >> 5;
    f16x8 bk[4][4];
#pragma unroll
    for (int tj = 0; tj < 4; ++tj) {
        int jt = jb8 * 16 + w * 4 + tj;
#pragma unroll
        for (int kst = 0; kst < 4; ++kst)
            bk[tj][kst] = *(const f16x8*)&KTu[((((size_t)kc_s * NB + b) * 128 + jt) * 4 + kst) * 512 + l * 8];
    }
    float dacc[2][4];
#pragma unroll
    for (int qc = 0; qc < 2; ++qc)
#pragma unroll
        for (int tj = 0; tj < 4; ++tj) dacc[qc][tj] = 0.f;

#pragma unroll 2
    for (int it = 0; it < 16; ++it) {
        int itile = is * 16 + it;
#pragma unroll
        for (int qc = 0; qc < 2; ++qc) {
            f16x8 aq[4];
#pragma unroll
            for (int kst = 0; kst < 4; ++kst)
                aq[kst] = *(const f16x8*)&QBu[((((size_t)qc * NB + b) * 64 + itile) * 4 + kst) * 512 + l * 8];
#pragma unroll
            for (int tj = 0; tj < 4; ++tj) {
                f32x4 c = {0.f, 0.f, 0.f, 0.f};
#pragma unroll
                for (int kst = 0; kst < 4; ++kst)
                    c = __builtin_amdgcn_mfma_f32_16x16x32_f16(aq[kst], bk[tj][kst], c, 0, 0, 0);
#pragma unroll
                for (int rr = 0; rr < 4; ++rr) dacc[qc][tj] += __builtin_amdgcn_exp2f(c[rr]);
            }
        }
    }
#pragma unroll
    for (int qc = 0; qc < 2; ++qc)
#pragma unroll
        for (int tj = 0; tj < 4; ++tj) {
            float v = dacc[qc][tj];
            v += __shfl_xor(v, 16, 64);
            v += __shfl_xor(v, 32, 64);
            if (lg == 0) {
                int br = qc * 2 + kc_s;
                int j = (jb8 * 16 + w * 4 + tj) * 16 + lr;
                d_part[(((size_t)is * 4 + br) * NB + b) * NJ + j] = v;
            }
        }
}

// ---------------- k_pmat: glds-staged bk, 64 i per block, 6 blocks/CU --------
// grid 2048: b=bid&7; r=bid>>3: jb=r&15, ib=r>>4 (0..15); 4 waves, wave owns 1 i-tile
__global__ __launch_bounds__(256, 6) void k_pmat(
    const unsigned short* __restrict__ KTu, const unsigned short* __restrict__ QBu,
    const float* __restrict__ d_part, unsigned short* __restrict__ P0) {
    __shared__ _Float16 bkS[2][8][512];         // 16 KB dbuf: frag f = kc*4+kst
    __shared__ unsigned short Ps[4][16][36];    // 4.6 KB per-wave transpose strips
    __shared__ float ivd[4][128];               // 2 KB
    int bid = blockIdx.x;
    int b = bid & 7, r = bid >> 3;
    int jb = r & 15, ib = r >> 4;
    int t = threadIdx.x, w = t >> 6, l = t & 63, lr = l & 15, lg = l >> 4;

    for (int e = t; e < 512; e += 256) {
        int br = e >> 7, jj = e & 127;
        size_t o = ((size_t)br * NB + b) * NJ + jb * 128 + jj;
        const size_t S = (size_t)4 * NB * NJ;
        ivd[br][jj] = 1.0f / (d_part[o] + d_part[o + S] + d_part[o + 2 * S] + d_part[o + 3 * S]);
    }

    // hoisted A fragments: 8 frags = 32 VGPR (wave's single i-tile)
    int itb = ib * 4 + w;
    f16x8 aq[2][4];
#pragma unroll
    for (int qc = 0; qc < 2; ++qc)
#pragma unroll
        for (int kst = 0; kst < 4; ++kst)
            aq[qc][kst] = *(const f16x8*)&QBu[((((size_t)qc * NB + b) * 64 + itb) * 4 + kst) * 512 + l * 8];

    // stage jc=0 into buf 0: wave w stages frags 2w, 2w+1
    {
        int jt = jb * 8;
#pragma unroll
        for (int ff = 0; ff < 2; ++ff) {
            int f = w * 2 + ff, kc = f >> 2, kst = f & 3;
            const unsigned short* src = &KTu[((((size_t)kc * NB + b) * 128 + jt) * 4 + kst) * 512 + l * 8];
            __builtin_amdgcn_global_load_lds((const AS1 unsigned int*)src,
                                             (AS3 unsigned int*)&bkS[0][f][0], 16, 0, 0);
        }
    }
    __syncthreads();

#pragma unroll 1
    for (int jc = 0; jc < 8; ++jc) {
        int cur = jc & 1;
        if (jc < 7) {
            int jt = jb * 8 + jc + 1;
#pragma unroll
            for (int ff = 0; ff < 2; ++ff) {
                int f = w * 2 + ff, kc = f >> 2, kst = f & 3;
                const unsigned short* src = &KTu[((((size_t)kc * NB + b) * 128 + jt) * 4 + kst) * 512 + l * 8];
                __builtin_amdgcn_global_load_lds((const AS1 unsigned int*)src,
                                                 (AS3 unsigned int*)&bkS[cur ^ 1][f][0], 16, 0, 0);
            }
        }
        float iv[4];
#pragma unroll
        for (int br = 0; br < 4; ++br) iv[br] = ivd[br][jc * 16 + lr];
        f32x4 pacc = {0.f, 0.f, 0.f, 0.f};
#pragma unroll
        for (int kc = 0; kc < 2; ++kc) {
            f16x8 bk[4];
#pragma unroll
            for (int kst = 0; kst < 4; ++kst)
                bk[kst] = *(const f16x8*)&bkS[cur][kc * 4 + kst][l * 8];
#pragma unroll
            for (int qc = 0; qc < 2; ++qc) {
                float ivb = iv[qc * 2 + kc];
                f32x4 c = {0.f, 0.f, 0.f, 0.f};
#pragma unroll
                for (int kst = 0; kst < 4; ++kst)
                    c = __builtin_amdgcn_mfma_f32_16x16x32_f16(aq[qc][kst], bk[kst], c, 0, 0, 0);
#pragma unroll
                for (int rr = 0; rr < 4; ++rr)
                    pacc[rr] += __builtin_amdgcn_exp2f(c[rr]) * ivb;
            }
        }
        // write C-frag to wave-private strip (cols (jc&1)*16 + lr)
#pragma unroll
        for (int rr = 0; rr < 4; ++rr)
            Ps[w][lg * 4 + rr][(jc & 1) * 16 + lr] = f2bf(pacc[rr]);
        if (jc & 1) {
            // read back as A-frag for k-chunk jb*4 + (jc>>1); coalesced 16B store
            unsigned short* Pg = P0 + (size_t)b * PBF;
            int kchunk = jb * 4 + (jc >> 1);
            s16x8 v = *(const s16x8*)&Ps[w][lr][lg * 8];
            size_t o = ((size_t)itb * 64 + kchunk) * 512 + l * 8;
            *(s16x8*)&Pg[o] = v;
        }
        __syncthreads();
    }
}

// ---------------- k_out: out = P @ MV^T; glds-shared B tiles, 4-jc dbuf stages ------
// grid 512: b=bid&7; r=bid>>3: vb=r&3, ibb=r>>2; 4 waves; wave w: it=ibb*4+w, all 8 vt
__global__ __launch_bounds__(256) void k_out(
    const unsigned short* __restrict__ P0, const unsigned short* __restrict__ MVf,
    float* __restrict__ out) {
    __shared__ s16x8 Bs[2][4][8][64];   // 64 KB: [buf][jj][vt][lane]
    int bid = blockIdx.x;
    int b = bid & 7, r = bid >> 3;
    int vb = r & 3, ibb = r >> 2;
    int t = threadIdx.x, w = t >> 6, l = t & 63, lr = l & 15, lg = l >> 4;
    int it = ibb * 4 + w;
    const unsigned short* pA = P0 + (size_t)b * PBF + ((size_t)it * 64) * 512 + l * 8;
    const unsigned short* MB = MVf + (((size_t)b * 32 + vb * 8) * 64) * 512;

    f32x4 acc[8];
#pragma unroll
    for (int vt = 0; vt < 8; ++vt) acc[vt] = (f32x4){0.f, 0.f, 0.f, 0.f};

#define STAGE(buf, jc0)                                                              \
    {                                                                                \
        _Pragma("unroll")                                                            \
        for (int ff = 0; ff < 8; ++ff) {                                             \
            int f = w * 8 + ff, jj = f >> 3, vt = f & 7;                             \
            const unsigned short* src = MB + ((size_t)vt * 64 + (jc0) + jj) * 512 + l * 8; \
            __builtin_amdgcn_global_load_lds((const AS1 unsigned int*)src,           \
                                             (AS3 unsigned int*)&Bs[buf][jj][vt][0], 16, 0, 0); \
        }                                                                            \
    }

    STAGE(0, 0)
    s16x8 pc[4], pn[4];
#pragma unroll
    for (int jj = 0; jj < 4; ++jj) pc[jj] = *(const s16x8*)&pA[(size_t)jj * 512];
    __syncthreads();

#pragma unroll 1
    for (int p = 0; p < 16; ++p) {
        int cur = p & 1;
        if (p < 15) {
            STAGE(cur ^ 1, (p + 1) * 4)
#pragma unroll
            for (int jj = 0; jj < 4; ++jj)
                pn[jj] = *(const s16x8*)&pA[(size_t)((p + 1) * 4 + jj) * 512];
        }
#pragma unroll
        for (int jj = 0; jj < 4; ++jj)
#pragma unroll
            for (int vt = 0; vt < 8; ++vt)
                acc[vt] = __builtin_amdgcn_mfma_f32_16x16x32_bf16(pc[jj], Bs[cur][jj][vt][l], acc[vt], 0, 0, 0);
        __syncthreads();
#pragma unroll
        for (int jj = 0; jj < 4; ++jj) pc[jj] = pn[jj];
    }
#undef STAGE
    float* ob = out + (size_t)b * 1048576;
    int i0 = it * 16;
#pragma unroll
    for (int vt = 0; vt < 8; ++vt)
#pragma unroll
        for (int rr = 0; rr < 4; ++rr) {
            int i = i0 + lg * 4 + rr;
            int v = vb * 128 + vt * 16 + lr;
            ob[(size_t)i * VD + v] = acc[vt][rr];
        }
}

extern "C" void kernel_launch(void* const* d_in, const int* in_sizes, int n_in,
                              void* d_out, int out_size, void* d_ws, size_t ws_size,
                              hipStream_t stream) {
    const float* m_key   = (const float*)d_in[0];
    const float* m_val   = (const float*)d_in[1];
    const float* q_key   = (const float*)d_in[2];
    const float* q_val   = (const float*)d_in[3];
    const float* p_m_key = (const float*)d_in[4];
    const float* p_q_key = (const float*)d_in[5];
    float* out = (float*)d_out;
    char* ws = (char*)d_ws;
    if (ws_size < WS_NEED) return;

    unsigned short* KT = (unsigned short*)(ws + WS_KT);
    unsigned short* QB = (unsigned short*)(ws + WS_QB);
    unsigned short* MV = (unsigned short*)(ws + WS_MV);
    float* d_part = (float*)(ws + WS_D);
    unsigned short* P0 = (unsigned short*)(ws + WS_P);

    k_prep_kq<<<640, 256, 0, stream>>>(m_key, p_m_key, q_key, p_q_key, KT, QB);
    k_stats<<<1920, 256, 0, stream>>>(KT, QB, m_val, q_val, d_part, MV, out);
    k_pmat<<<2048, 256, 0, stream>>>(KT, QB, d_part, P0);
    k_out<<<512, 256, 0, stream>>>(P0, MV, out);
}

// Round 17
// 92.793 us; speedup vs baseline: 1.0341x; 1.0341x over previous
//
#include <hip/hip_runtime.h>
#include <hip/hip_bf16.h>

#define DEVI __device__ __forceinline__
#define AS1 __attribute__((address_space(1)))
#define AS3 __attribute__((address_space(3)))

typedef float f32x4 __attribute__((ext_vector_type(4)));
typedef _Float16 f16x8 __attribute__((ext_vector_type(8)));
typedef short s16x8 __attribute__((ext_vector_type(8)));

constexpr int NB = 8;     // batch
constexpr int HW = 1024;  // i (query) dim
constexpr int KD = 128;   // QK reduction dim
constexpr int VD = 512;   // value dim
constexpr int NJ = 2048;  // j (key/col) dim
constexpr float LOG2E = 1.44269504088896f;

// Fragment-major layouts: [..tile..][..k-chunk..][lane 64][elem 8]
// QB f16  [2 src][8 b][64 it][4 kc][512]   (pre-scaled by log2(e))
// KT f16  [2 src][8 b][128 jt][4 kc][512]
// MV bf16 [8 b][32 vt][64 jc][512]
// P  bf16 [8 b][64 it][64 kchunk][512]
constexpr size_t WS_KT = 0;                                    // 8.39 MB
constexpr size_t WS_QB = WS_KT + (size_t)2*NB*NJ*KD*2;         // 4.19 MB
constexpr size_t WS_MV = WS_QB + (size_t)2*NB*HW*KD*2;         // 16.78 MB
constexpr size_t WS_D  = WS_MV + (size_t)NB*VD*NJ*2;           // 2.10 MB
constexpr size_t WS_P  = WS_D  + (size_t)4*4*NB*NJ*4;          // 33.55 MB
constexpr size_t WS_NEED = WS_P + (size_t)NB*HW*NJ*2;          // ~65 MB total
constexpr size_t PBF = (size_t)64*64*512;                      // P shorts per batch

DEVI unsigned short f2bf(float x) {
    unsigned int u = __builtin_bit_cast(unsigned int, x);
    u += 0x7fffu + ((u >> 16) & 1u);
    return (unsigned short)(u >> 16);
}

// ---------------- k_prep: 4 sections, all streams coalesced (round-11/14 proven) ----
// [0,512): KT transpose; [512,1536): MV cvt; [1536,1664): QB cvt; [1664,2048): qval
__global__ __launch_bounds__(256) void k_prep(
    const float* __restrict__ k0, const float* __restrict__ k1,
    const float* __restrict__ q0, const float* __restrict__ q1,
    const float* __restrict__ mv, const float* __restrict__ qv,
    unsigned short* __restrict__ KT, unsigned short* __restrict__ QB,
    unsigned short* __restrict__ MV, float* __restrict__ out) {
    __shared__ _Float16 Lt[128][138];   // 35.3 KB, shared by all sections
    int bid = blockIdx.x;
    int t = threadIdx.x;
    int w = t >> 6, l = t & 63, lr = l & 15, lg = l >> 4;

    if (bid < 512) {
        _Float16(*Lk)[136] = (_Float16(*)[136])&Lt[0][0];
        int jt64 = bid & 31, b = (bid >> 5) & 7, src = bid >> 8;
        const float* K = (src ? k1 : k0) + (size_t)b * KD * NJ;
#pragma unroll
        for (int rd = 0; rd < 8; ++rd) {
            int task = t + rd * 256;
            int d = task >> 4, j4 = (task & 15) * 4;
            float4 v = *(const float4*)&K[(size_t)d * NJ + jt64 * 64 + j4];
            Lk[j4 + 0][d] = (_Float16)v.x;
            Lk[j4 + 1][d] = (_Float16)v.y;
            Lk[j4 + 2][d] = (_Float16)v.z;
            Lk[j4 + 3][d] = (_Float16)v.w;
        }
        __syncthreads();
        int jt = jt64 * 4 + w;
#pragma unroll
        for (int kc = 0; kc < 4; ++kc) {
            f16x8 v = *(const f16x8*)&Lk[w * 16 + lr][kc * 32 + lg * 8];
            *(f16x8*)&KT[((((size_t)src * NB + b) * 128 + jt) * 4 + kc) * 512 + l * 8] = v;
        }
        return;
    }
    if (bid < 1536) {
        // ---- MV cvt: tile 16 v x 512 j ----
        unsigned short(*Lv)[522] = (unsigned short(*)[522])&Lt[0][0];  // 16.7 KB
        int bid2 = bid - 512;
        int jq = bid2 & 3, vt = (bid2 >> 2) & 31, b = bid2 >> 7;
        const float* src = mv + (size_t)b * VD * NJ + (size_t)(vt * 16) * NJ + jq * 512;
#pragma unroll
        for (int rd = 0; rd < 8; ++rd) {
            int idx = rd * 256 + t;
            int row = idx >> 7, c4 = (idx & 127) * 4;
            float4 v = *(const float4*)&src[(size_t)row * NJ + c4];
            Lv[row][c4 + 0] = f2bf(v.x);
            Lv[row][c4 + 1] = f2bf(v.y);
            Lv[row][c4 + 2] = f2bf(v.z);
            Lv[row][c4 + 3] = f2bf(v.w);
        }
        __syncthreads();
#pragma unroll
        for (int rd = 0; rd < 4; ++rd) {
            int f = rd * 4 + w;
            s16x8 v = *(const s16x8*)&Lv[lr][f * 32 + lg * 8];
            *(s16x8*)&MV[(((size_t)b * 32 + vt) * 64 + jq * 16 + f) * 512 + l * 8] = v;
        }
        return;
    }
    if (bid < 1664) {
        // ---- QB cvt: tile 128 i x 128 d, x LOG2E ----
        int bid3 = bid - 1536;
        int itq = bid3 & 7, b = (bid3 >> 3) & 7, src_q = bid3 >> 6;
        const float* q = (src_q ? q1 : q0) + (size_t)(b * HW + itq * 128) * KD;
#pragma unroll
        for (int rd = 0; rd < 16; ++rd) {
            int idx = rd * 256 + t;
            int row = idx >> 5, c4 = (idx & 31) * 4;
            float4 v = *(const float4*)&q[(size_t)row * KD + c4];
            Lt[row][c4 + 0] = (_Float16)(v.x * LOG2E);
            Lt[row][c4 + 1] = (_Float16)(v.y * LOG2E);
            Lt[row][c4 + 2] = (_Float16)(v.z * LOG2E);
            Lt[row][c4 + 3] = (_Float16)(v.w * LOG2E);
        }
        __syncthreads();
#pragma unroll
        for (int rd = 0; rd < 8; ++rd) {
            int f = rd * 4 + w;
            int it_l = f >> 2, kc = f & 3;
            f16x8 v = *(const f16x8*)&Lt[it_l * 16 + lr][kc * 32 + lg * 8];
            *(f16x8*)&QB[((((size_t)src_q * NB + b) * 64 + itq * 8 + it_l) * 4 + kc) * 512 + l * 8] = v;
        }
        return;
    }
    // ---- qval copy ----
    const int NQV = NB * VD * HW / 4;
    for (int t3 = (bid - 1664) * 256 + t; t3 < NQV; t3 += 384 * 256) {
        int b = t3 >> 17, t4 = t3 & 131071;
        float4 v = ((const float4*)qv)[t3];
        ((float4*)(out + (size_t)b * 1048576 + 524288))[t4] = v;
    }
}

// ---------------- k_stats: glds-staged aq (block-shared), reg-hoisted bk ----------
// grid 1024: b=bid&7; r=bid>>3: jb=r&15, is=(r>>4)&3, kc=r>>6; 4 waves
// Mirror of k_pmat: aq (shared by all 4 waves) double-buffered via global_load_lds;
// bk (wave-private, 2 jt per wave) hoisted in registers.
__global__ __launch_bounds__(256, 4) void k_stats(
    const unsigned short* __restrict__ KTu, const unsigned short* __restrict__ QBu,
    float* __restrict__ d_part) {
    __shared__ _Float16 aqS[2][8][512];   // 16 KB dbuf: frag f = qc*4+kst
    int bid = blockIdx.x;
    int b = bid & 7, r = bid >> 3;
    int jb = r & 15, is = (r >> 4) & 3, kc_s = r >> 6;
    int t = threadIdx.x, w = t >> 6, l = t & 63, lr = l & 15, lg = l >> 4;

    // hoisted B fragments: 2 jt per wave = 32 VGPR
    f16x8 bk[2][4];
#pragma unroll
    for (int tj = 0; tj < 2; ++tj) {
        int jt = jb * 8 + w * 2 + tj;
#pragma unroll
        for (int kst = 0; kst < 4; ++kst)
            bk[tj][kst] = *(const f16x8*)&KTu[((((size_t)kc_s * NB + b) * 128 + jt) * 4 + kst) * 512 + l * 8];
    }
    float dacc[2][2];
    dacc[0][0] = dacc[0][1] = dacc[1][0] = dacc[1][1] = 0.f;

    // stage it=0 into buf 0: wave w stages frags 2w, 2w+1 (f: qc = f>>2, kst = f&3)
    {
        int itile = is * 16;
#pragma unroll
        for (int ff = 0; ff < 2; ++ff) {
            int f = w * 2 + ff, qc = f >> 2, kst = f & 3;
            const unsigned short* src = &QBu[((((size_t)qc * NB + b) * 64 + itile) * 4 + kst) * 512 + l * 8];
            __builtin_amdgcn_global_load_lds((const AS1 unsigned int*)src,
                                             (AS3 unsigned int*)&aqS[0][f][0], 16, 0, 0);
        }
    }
    __syncthreads();

#pragma unroll 1
    for (int it = 0; it < 16; ++it) {
        int cur = it & 1;
        if (it < 15) {
            int itile = is * 16 + it + 1;
#pragma unroll
            for (int ff = 0; ff < 2; ++ff) {
                int f = w * 2 + ff, qc = f >> 2, kst = f & 3;
                const unsigned short* src = &QBu[((((size_t)qc * NB + b) * 64 + itile) * 4 + kst) * 512 + l * 8];
                __builtin_amdgcn_global_load_lds((const AS1 unsigned int*)src,
                                                 (AS3 unsigned int*)&aqS[cur ^ 1][f][0], 16, 0, 0);
            }
        }
#pragma unroll
        for (int qc = 0; qc < 2; ++qc) {
            f16x8 aq[4];
#pragma unroll
            for (int kst = 0; kst < 4; ++kst)
                aq[kst] = *(const f16x8*)&aqS[cur][qc * 4 + kst][l * 8];
#pragma unroll
            for (int tj = 0; tj < 2; ++tj) {
                f32x4 c = {0.f, 0.f, 0.f, 0.f};
#pragma unroll
                for (int kst = 0; kst < 4; ++kst)
                    c = __builtin_amdgcn_mfma_f32_16x16x32_f16(aq[kst], bk[tj][kst], c, 0, 0, 0);
#pragma unroll
                for (int rr = 0; rr < 4; ++rr) dacc[qc][tj] += __builtin_amdgcn_exp2f(c[rr]);
            }
        }
        __syncthreads();
    }
#pragma unroll
    for (int qc = 0; qc < 2; ++qc)
#pragma unroll
        for (int tj = 0; tj < 2; ++tj) {
            float v = dacc[qc][tj];
            v += __shfl_xor(v, 16, 64);
            v += __shfl_xor(v, 32, 64);
            if (lg == 0) {
                int br = qc * 2 + kc_s;
                int j = (jb * 8 + w * 2 + tj) * 16 + lr;
                d_part[(((size_t)is * 4 + br) * NB + b) * NJ + j] = v;
            }
        }
}

// ---------------- k_pmat: glds-staged bk, 64 i per block, 6 blocks/CU --------
// grid 2048: b=bid&7; r=bid>>3: jb=r&15, ib=r>>4 (0..15); 4 waves, wave owns 1 i-tile
__global__ __launch_bounds__(256, 6) void k_pmat(
    const unsigned short* __restrict__ KTu, const unsigned short* __restrict__ QBu,
    const float* __restrict__ d_part, unsigned short* __restrict__ P0) {
    __shared__ _Float16 bkS[2][8][512];         // 16 KB dbuf: frag f = kc*4+kst
    __shared__ unsigned short Ps[4][16][36];    // 4.6 KB per-wave transpose strips
    __shared__ float ivd[4][128];               // 2 KB
    int bid = blockIdx.x;
    int b = bid & 7, r = bid >> 3;
    int jb = r & 15, ib = r >> 4;
    int t = threadIdx.x, w = t >> 6, l = t & 63, lr = l & 15, lg = l >> 4;

    for (int e = t; e < 512; e += 256) {
        int br = e >> 7, jj = e & 127;
        size_t o = ((size_t)br * NB + b) * NJ + jb * 128 + jj;
        const size_t S = (size_t)4 * NB * NJ;
        ivd[br][jj] = 1.0f / (d_part[o] + d_part[o + S] + d_part[o + 2 * S] + d_part[o + 3 * S]);
    }

    // hoisted A fragments: 8 frags = 32 VGPR (wave's single i-tile)
    int itb = ib * 4 + w;
    f16x8 aq[2][4];
#pragma unroll
    for (int qc = 0; qc < 2; ++qc)
#pragma unroll
        for (int kst = 0; kst < 4; ++kst)
            aq[qc][kst] = *(const f16x8*)&QBu[((((size_t)qc * NB + b) * 64 + itb) * 4 + kst) * 512 + l * 8];

    // stage jc=0 into buf 0: wave w stages frags 2w, 2w+1
    {
        int jt = jb * 8;
#pragma unroll
        for (int ff = 0; ff < 2; ++ff) {
            int f = w * 2 + ff, kc = f >> 2, kst = f & 3;
            const unsigned short* src = &KTu[((((size_t)kc * NB + b) * 128 + jt) * 4 + kst) * 512 + l * 8];
            __builtin_amdgcn_global_load_lds((const AS1 unsigned int*)src,
                                             (AS3 unsigned int*)&bkS[0][f][0], 16, 0, 0);
        }
    }
    __syncthreads();

#pragma unroll 1
    for (int jc = 0; jc < 8; ++jc) {
        int cur = jc & 1;
        if (jc < 7) {
            int jt = jb * 8 + jc + 1;
#pragma unroll
            for (int ff = 0; ff < 2; ++ff) {
                int f = w * 2 + ff, kc = f >> 2, kst = f & 3;
                const unsigned short* src = &KTu[((((size_t)kc * NB + b) * 128 + jt) * 4 + kst) * 512 + l * 8];
                __builtin_amdgcn_global_load_lds((const AS1 unsigned int*)src,
                                                 (AS3 unsigned int*)&bkS[cur ^ 1][f][0], 16, 0, 0);
            }
        }
        float iv[4];
#pragma unroll
        for (int br = 0; br < 4; ++br) iv[br] = ivd[br][jc * 16 + lr];
        f32x4 pacc = {0.f, 0.f, 0.f, 0.f};
#pragma unroll
        for (int kc = 0; kc < 2; ++kc) {
            f16x8 bk[4];
#pragma unroll
            for (int kst = 0; kst < 4; ++kst)
                bk[kst] = *(const f16x8*)&bkS[cur][kc * 4 + kst][l * 8];
#pragma unroll
            for (int qc = 0; qc < 2; ++qc) {
                float ivb = iv[qc * 2 + kc];
                f32x4 c = {0.f, 0.f, 0.f, 0.f};
#pragma unroll
                for (int kst = 0; kst < 4; ++kst)
                    c = __builtin_amdgcn_mfma_f32_16x16x32_f16(aq[qc][kst], bk[kst], c, 0, 0, 0);
#pragma unroll
                for (int rr = 0; rr < 4; ++rr)
                    pacc[rr] += __builtin_amdgcn_exp2f(c[rr]) * ivb;
            }
        }
        // write C-frag to wave-private strip (cols (jc&1)*16 + lr)
#pragma unroll
        for (int rr = 0; rr < 4; ++rr)
            Ps[w][lg * 4 + rr][(jc & 1) * 16 + lr] = f2bf(pacc[rr]);
        if (jc & 1) {
            // read back as A-frag for k-chunk jb*4 + (jc>>1); coalesced 16B store
            unsigned short* Pg = P0 + (size_t)b * PBF;
            int kchunk = jb * 4 + (jc >> 1);
            s16x8 v = *(const s16x8*)&Ps[w][lr][lg * 8];
            size_t o = ((size_t)itb * 64 + kchunk) * 512 + l * 8;
            *(s16x8*)&Pg[o] = v;
        }
        __syncthreads();
    }
}

// ---------------- k_out: out = P @ MV^T; glds-shared B tiles, 4-jc dbuf stages ------
// grid 512: b=bid&7; r=bid>>3: vb=r&3, ibb=r>>2; 4 waves; wave w: it=ibb*4+w, all 8 vt
__global__ __launch_bounds__(256) void k_out(
    const unsigned short* __restrict__ P0, const unsigned short* __restrict__ MVf,
    float* __restrict__ out) {
    __shared__ s16x8 Bs[2][4][8][64];   // 64 KB: [buf][jj][vt][lane]
    int bid = blockIdx.x;
    int b = bid & 7, r = bid >> 3;
    int vb = r & 3, ibb = r >> 2;
    int t = threadIdx.x, w = t >> 6, l = t & 63, lr = l & 15, lg = l >> 4;
    int it = ibb * 4 + w;
    const unsigned short* pA = P0 + (size_t)b * PBF + ((size_t)it * 64) * 512 + l * 8;
    const unsigned short* MB = MVf + (((size_t)b * 32 + vb * 8) * 64) * 512;

    f32x4 acc[8];
#pragma unroll
    for (int vt = 0; vt < 8; ++vt) acc[vt] = (f32x4){0.f, 0.f, 0.f, 0.f};

#define STAGE(buf, jc0)                                                              \
    {                                                                                \
        _Pragma("unroll")                                                            \
        for (int ff = 0; ff < 8; ++ff) {                                             \
            int f = w * 8 + ff, jj = f >> 3, vt = f & 7;                             \
            const unsigned short* src = MB + ((size_t)vt * 64 + (jc0) + jj) * 512 + l * 8; \
            __builtin_amdgcn_global_load_lds((const AS1 unsigned int*)src,           \
                                             (AS3 unsigned int*)&Bs[buf][jj][vt][0], 16, 0, 0); \
        }                                                                            \
    }

    STAGE(0, 0)
    s16x8 pc[4], pn[4];
#pragma unroll
    for (int jj = 0; jj < 4; ++jj) pc[jj] = *(const s16x8*)&pA[(size_t)jj * 512];
    __syncthreads();

#pragma unroll 1
    for (int p = 0; p < 16; ++p) {
        int cur = p & 1;
        if (p < 15) {
            STAGE(cur ^ 1, (p + 1) * 4)
#pragma unroll
            for (int jj = 0; jj < 4; ++jj)
                pn[jj] = *(const s16x8*)&pA[(size_t)((p + 1) * 4 + jj) * 512];
        }
#pragma unroll
        for (int jj = 0; jj < 4; ++jj)
#pragma unroll
            for (int vt = 0; vt < 8; ++vt)
                acc[vt] = __builtin_amdgcn_mfma_f32_16x16x32_bf16(pc[jj], Bs[cur][jj][vt][l], acc[vt], 0, 0, 0);
        __syncthreads();
#pragma unroll
        for (int jj = 0; jj < 4; ++jj) pc[jj] = pn[jj];
    }
#undef STAGE
    float* ob = out + (size_t)b * 1048576;
    int i0 = it * 16;
#pragma unroll
    for (int vt = 0; vt < 8; ++vt)
#pragma unroll
        for (int rr = 0; rr < 4; ++rr) {
            int i = i0 + lg * 4 + rr;
            int v = vb * 128 + vt * 16 + lr;
            ob[(size_t)i * VD + v] = acc[vt][rr];
        }
}

extern "C" void kernel_launch(void* const* d_in, const int* in_sizes, int n_in,
                              void* d_out, int out_size, void* d_ws, size_t ws_size,
                              hipStream_t stream) {
    const float* m_key   = (const float*)d_in[0];
    const float* m_val   = (const float*)d_in[1];
    const float* q_key   = (const float*)d_in[2];
    const float* q_val   = (const float*)d_in[3];
    const float* p_m_key = (const float*)d_in[4];
    const float* p_q_key = (const float*)d_in[5];
    float* out = (float*)d_out;
    char* ws = (char*)d_ws;
    if (ws_size < WS_NEED) return;

    unsigned short* KT = (unsigned short*)(ws + WS_KT);
    unsigned short* QB = (unsigned short*)(ws + WS_QB);
    unsigned short* MV = (unsigned short*)(ws + WS_MV);
    float* d_part = (float*)(ws + WS_D);
    unsigned short* P0 = (unsigned short*)(ws + WS_P);

    k_prep<<<2048, 256, 0, stream>>>(m_key, p_m_key, q_key, p_q_key, m_val, q_val,
                                     KT, QB, MV, out);
    k_stats<<<1024, 256, 0, stream>>>(KT, QB, d_part);
    k_pmat<<<2048, 256, 0, stream>>>(KT, QB, d_part, P0);
    k_out<<<512, 256, 0, stream>>>(P0, MV, out);
}